// Round 6
// baseline (32.231 us; speedup 1.0000x reference)
//
#include <hip/hip_runtime.h>
#include <hip/hip_bf16.h>

// FilterbankLinear: out[b, j*8+o] = sum_{c,t} x[b,c,s_j+t] * w[j*8+o, c*32+t]
// s_j = j (j<4063), s_4063 = 4064.
// Block = 8 windows, 8 waves (512 thr), one window/wave, grid 508 (~2 blk/CU).
// x: reg-staged fp32 -> cvt bf16 -> ds_write_b64 into 144B-stride rows (9x16B,
//    odd chunk count -> conflict-free b128 reads), double-buffered, counted
//    vmcnt, one lgkmcnt(0)+s_barrier per channel. Rolled 2-step loop.
// w: direct float4 register prefetch (unchanged, proven).

#define NF 4096
#define NC 21
#define WIN 32
#define OC 8
#define NWIN 4064
#define NKTOT (OC * NWIN)
#define DD (NC * WIN)       // 672
#define JB 8
#define NBLK (NWIN / JB)    // 508
#define XROW 144            // bf16 LDS row stride (72 shorts; 68 valid + 4 pad)
#define XBUF (32 * XROW)    // 4608 B per buffer

typedef short short4v __attribute__((ext_vector_type(4)));
typedef short short8 __attribute__((ext_vector_type(8)));
typedef float f32x4 __attribute__((ext_vector_type(4)));

static __device__ __forceinline__ short f2bf(float f) {
  __bf16 h = (__bf16)f;
  return __builtin_bit_cast(short, h);
}
static __device__ __forceinline__ short4v cvt4(float4 v) {
  short4v s;
  s[0] = f2bf(v.x); s[1] = f2bf(v.y); s[2] = f2bf(v.z); s[3] = f2bf(v.w);
  return s;
}
static __device__ __forceinline__ short8 pk8w(float4 a, float4 b) {
  short8 v;
  v[0]=f2bf(a.x); v[1]=f2bf(a.y); v[2]=f2bf(a.z); v[3]=f2bf(a.w);
  v[4]=f2bf(b.x); v[5]=f2bf(b.y); v[6]=f2bf(b.z); v[7]=f2bf(b.w);
  return v;
}
// select shorts [u, u+8) from concat(lo, hi); u wave-uniform 0..7, static idx
#define SELC(K) { \
  fa0[0]=((K)+0<8?r0a[(K)+0]:r1a[(K)-8+0]); fa0[1]=((K)+1<8?r0a[(K)+1]:r1a[(K)-8+1]); \
  fa0[2]=((K)+2<8?r0a[(K)+2]:r1a[(K)-8+2]); fa0[3]=((K)+3<8?r0a[(K)+3]:r1a[(K)-8+3]); \
  fa0[4]=((K)+4<8?r0a[(K)+4]:r1a[(K)-8+4]); fa0[5]=((K)+5<8?r0a[(K)+5]:r1a[(K)-8+5]); \
  fa0[6]=((K)+6<8?r0a[(K)+6]:r1a[(K)-8+6]); fa0[7]=((K)+7<8?r0a[(K)+7]:r1a[(K)-8+7]); \
  fa1[0]=((K)+0<8?r0b[(K)+0]:r1b[(K)-8+0]); fa1[1]=((K)+1<8?r0b[(K)+1]:r1b[(K)-8+1]); \
  fa1[2]=((K)+2<8?r0b[(K)+2]:r1b[(K)-8+2]); fa1[3]=((K)+3<8?r0b[(K)+3]:r1b[(K)-8+3]); \
  fa1[4]=((K)+4<8?r0b[(K)+4]:r1b[(K)-8+4]); fa1[5]=((K)+5<8?r0b[(K)+5]:r1b[(K)-8+5]); \
  fa1[6]=((K)+6<8?r0b[(K)+6]:r1b[(K)-8+6]); fa1[7]=((K)+7<8?r0b[(K)+7]:r1b[(K)-8+7]); }

static __device__ __forceinline__ void wait_vmcnt(int nv) {
  if (nv == 6) asm volatile("s_waitcnt vmcnt(6)" ::: "memory");
  else         asm volatile("s_waitcnt vmcnt(4)" ::: "memory");
}

__global__ __launch_bounds__(512) void fb_v6(const float* __restrict__ x,
                                             const float* __restrict__ w,
                                             float* __restrict__ out) {
  __shared__ __align__(16) char xlds[2 * XBUF];
  const int lane = threadIdx.x & 63;
  const int wv   = threadIdx.x >> 6;
  const int tid  = threadIdx.x;

  // bijective XCD swizzle (nwg=508: q=63, r=4)
  const int orig = blockIdx.x;
  const int xcd = orig & 7, sidx = orig >> 3;
  const int blk = (xcd < 4 ? xcd * 64 : 256 + (xcd - 4) * 63) + sidx;
  const int j0 = blk * JB;                          // multiple of 8 -> 16B aligned
  const int a0 = (j0 < NF - 68) ? j0 : (NF - 68);   // 4028 also 4-aligned

  const int n  = lane & 15;
  const int o  = n & 7;
  const int k4 = lane >> 4;                         // k-slice /8

  const int jg = j0 + wv;
  const int sv = (jg == NWIN - 1) ? (NF - WIN) : jg;
  const int rj = sv - a0;                           // 0..36
  const int u  = rj & 7;
  const int ro0 = n * XROW + ((rj >> 3) + k4) * 16;
  const int ro1 = ro0 + 16 * XROW;

  // staging coords: thread tid loads chunk tid; ALL waves also load chunk
  // 512+lane (clamped) -- duplicate across waves, keeps vmcnt uniform.
  const int b0 = tid / 17, p0 = tid - b0 * 17;
  int q2 = 512 + lane; if (q2 > 543) q2 = 543;
  const int b2 = q2 / 17, p2 = q2 - b2 * 17;
  const float* xs0 = x + (size_t)b0 * (NC * NF) + a0 + p0 * 4;
  const float* xs2 = x + (size_t)b2 * (NC * NF) + a0 + p2 * 4;
  const int wd0 = b0 * XROW + p0 * 8;
  const int wd2 = b2 * XROW + p2 * 8;

  const float* wn = w + ((size_t)jg * OC + o) * DD + k4 * 8;

  f32x4 acc0 = {0,0,0,0}, acc1 = {0,0,0,0};

  // ---- prologue: ch0 -> buf0; ch1 -> regs; w(0) -> regs ----
  float4 t0a = *(const float4*)(xs0);
  float4 t0b = *(const float4*)(xs2);
  xs0 += NF; xs2 += NF;
  float4 A0 = *(const float4*)(xs0);
  float4 A1 = *(const float4*)(xs2);
  xs0 += NF; xs2 += NF;
  float4 wa = *(const float4*)(wn), wb = *(const float4*)(wn + 4);
  wn += WIN;
  wait_vmcnt(4);                       // t0a,t0b done; A0,A1,wa,wb in flight
  *(short4v*)(xlds + wd0) = cvt4(t0a);
  *(short4v*)(xlds + wd2) = cvt4(t0b);
  asm volatile("s_waitcnt lgkmcnt(0)" ::: "memory");
  __builtin_amdgcn_s_barrier();
  __builtin_amdgcn_sched_barrier(0);

  float4 B0, B1;

#define STEP(C, C0, C1, N0, N1) {                                              \
    if ((C) + 2 < NC) {                                                        \
      N0 = *(const float4*)(xs0); N1 = *(const float4*)(xs2);                  \
      xs0 += NF; xs2 += NF;                                                    \
    }                                                                          \
    float4 wan = {0,0,0,0}, wbn = {0,0,0,0};                                   \
    if ((C) + 1 < NC) {                                                        \
      wan = *(const float4*)(wn); wbn = *(const float4*)(wn + 4); wn += WIN;   \
      wait_vmcnt(((C) + 2 < NC) ? 6 : 4);    /* x(C+1) regs ready */           \
      char* xw = xlds + (((C) + 1) & 1) * XBUF;                                \
      *(short4v*)(xw + wd0) = cvt4(C0);                                        \
      *(short4v*)(xw + wd2) = cvt4(C1);                                        \
    }                                                                          \
    const char* xb = xlds + ((C) & 1) * XBUF;                                  \
    short8 r0a = *(const short8*)(xb + ro0);                                   \
    short8 r1a = *(const short8*)(xb + ro0 + 16);                              \
    short8 r0b = *(const short8*)(xb + ro1);                                   \
    short8 r1b = *(const short8*)(xb + ro1 + 16);                              \
    short8 fbw = pk8w(wa, wb);                                                 \
    short8 fa0, fa1;                                                           \
    switch (u) {                                                               \
      case 0: SELC(0); break; case 1: SELC(1); break;                          \
      case 2: SELC(2); break; case 3: SELC(3); break;                          \
      case 4: SELC(4); break; case 5: SELC(5); break;                          \
      case 6: SELC(6); break; default: SELC(7); break;                         \
    }                                                                          \
    acc0 = __builtin_amdgcn_mfma_f32_16x16x32_bf16(fa0, fbw, acc0, 0, 0, 0);   \
    acc1 = __builtin_amdgcn_mfma_f32_16x16x32_bf16(fa1, fbw, acc1, 0, 0, 0);   \
    wa = wan; wb = wbn;                                                        \
    asm volatile("s_waitcnt lgkmcnt(0)" ::: "memory");                         \
    __builtin_amdgcn_s_barrier();                                              \
    __builtin_amdgcn_sched_barrier(0);                                         \
  }

  for (int t = 0; t < 10; ++t) {
    STEP(2 * t,     A0, A1, B0, B1);
    STEP(2 * t + 1, B0, B1, A0, A1);
  }
  STEP(20, A0, A1, B0, B1);   // compute-only tail (no loads, no writes)

#undef STEP

  if (n < 8) {
    const int m0 = k4 * 4;
    #pragma unroll
    for (int e = 0; e < 4; ++e) {
      out[(size_t)(m0 + e)      * NKTOT + (size_t)jg * OC + n] = acc0[e];
      out[(size_t)(m0 + e + 16) * NKTOT + (size_t)jg * OC + n] = acc1[e];
    }
  }
}

extern "C" void kernel_launch(void* const* d_in, const int* in_sizes, int n_in,
                              void* d_out, int out_size, void* d_ws, size_t ws_size,
                              hipStream_t stream) {
  const float* x = (const float*)d_in[0];
  const float* w = (const float*)d_in[1];
  float* out = (float*)d_out;
  dim3 grid(NBLK), block(512);
  hipLaunchKernelGGL(fb_v6, grid, block, 0, stream, x, w, out);
}